// Round 5
// baseline (203.285 us; speedup 1.0000x reference)
//
#include <hip/hip_runtime.h>
#include <hip/hip_bf16.h>
#include <stdint.h>

// ============================================================================
// Fused causal self-attention block: QKV projection + flash attention.
// bf16 MFMA. No-max softmax (scores bounded; log2e folded into Q scale).
// Swapped QK^T (S^T) + transposed PV (O^T) so P stores are b64 and partial-O
// stores are b64. P LDS layout bank-optimal (stride-72 rows, no xor).
// kv-chunks <=8 tiles -> 1152 blocks x 4 waves; single-buffered K tile keeps
// LDS at 25.6KB -> 4 blocks/CU resident (16 waves/CU). V transposed inside
// k_qkv epilogue (no separate kernel, no row-major V buffer).
// ============================================================================

typedef __bf16 bf16x8 __attribute__((ext_vector_type(8)));
typedef float  f32x4  __attribute__((ext_vector_type(4)));
typedef unsigned int u32x4 __attribute__((ext_vector_type(4)));
typedef unsigned int u32x2 __attribute__((ext_vector_type(2)));

using bf16 = __hip_bfloat16;

#define AS1 __attribute__((address_space(1)))
#define AS3 __attribute__((address_space(3)))

__device__ __forceinline__ void gl_lds16(const void* g, void* l) {
  __builtin_amdgcn_global_load_lds((AS1 uint32_t*)g, (AS3 uint32_t*)l, 16, 0, 0);
}

// ---------------------------------------------------------------------------
// 1) W [1024][128] fp32 -> Wt[z][128][1024] bf16 (transpose via LDS tile)
// ---------------------------------------------------------------------------
__global__ __launch_bounds__(256) void k_wt(const float* __restrict__ Wq,
                                            const float* __restrict__ Wk,
                                            const float* __restrict__ Wv,
                                            bf16* __restrict__ Wt) {
  __shared__ bf16 t[64][72];
  const float* W = blockIdx.z == 0 ? Wq : (blockIdx.z == 1 ? Wk : Wv);
  int k0 = blockIdx.x * 64, n0 = blockIdx.y * 64;
  int tid = threadIdx.x;
  int r = tid >> 4, c4 = (tid & 15) * 4;
#pragma unroll
  for (int s = 0; s < 4; ++s) {
    int rr = r + s * 16;
    float4 v = *(const float4*)(W + (size_t)(k0 + rr) * 128 + n0 + c4);
    t[rr][c4 + 0] = __float2bfloat16(v.x);
    t[rr][c4 + 1] = __float2bfloat16(v.y);
    t[rr][c4 + 2] = __float2bfloat16(v.z);
    t[rr][c4 + 3] = __float2bfloat16(v.w);
  }
  __syncthreads();
  bf16* out = Wt + (size_t)blockIdx.z * 128 * 1024;
#pragma unroll
  for (int s = 0; s < 4; ++s) {
    int rn = r + s * 16;
    union { bf16 h[4]; u32x2 v; } u;
    u.h[0] = t[c4 + 0][rn]; u.h[1] = t[c4 + 1][rn];
    u.h[2] = t[c4 + 2][rn]; u.h[3] = t[c4 + 3][rn];
    *(u32x2*)(out + (size_t)(n0 + rn) * 1024 + k0 + c4) = u.v;
  }
}

// ---------------------------------------------------------------------------
// 2) fused QKV projection + in-kernel V transpose. Reads f32 X once.
//    BM=64, BK=32, 512 thr = 8 waves (2x4). Q pre-scaled log2(e)/sqrt(128).
//    Epilogue: Q,K stored row-major; V bounced through LDS -> Vt [B][128][S].
// ---------------------------------------------------------------------------
__global__ __launch_bounds__(512) void k_qkv(const float* __restrict__ X,
                                             const bf16* __restrict__ Wt,
                                             const float* __restrict__ bq,
                                             const float* __restrict__ bk,
                                             const float* __restrict__ bv,
                                             bf16* __restrict__ Qo,
                                             bf16* __restrict__ Ko,
                                             bf16* __restrict__ Vt) {
  __shared__ __align__(16) char smem[65536];
  float* Xs = (float*)smem;                  // [2][64*32] f32, 16 KB
  bf16* Ws = (bf16*)(smem + 16384);          // [2][3*128*32] bf16, 48 KB
  bf16* Vs = (bf16*)smem;                    // epilogue: [64][136], 17.4 KB

  const int m0 = blockIdx.x * 64;
  const int tid = threadIdx.x;
  const int lane = tid & 63;
  const int li = lane & 15, g = lane >> 4;
  const int wid = tid >> 6;
  const int wm = wid >> 2, wn = wid & 3;

  const int xr = tid >> 3;
  const int xc32 = (tid & 7) >> 1;
  const int xhf = tid & 1;
  const int wr = tid >> 2;
  const int wc = tid & 3;

  f32x4 acc[3][2][2] = {};

  {
    gl_lds16(X + (size_t)(m0 + xr) * 1024 + (xc32 ^ (xr & 3)) * 8 + xhf * 4,
             Xs + tid * 4);
#pragma unroll
    for (int z = 0; z < 3; ++z)
      gl_lds16(Wt + (size_t)z * 131072 + (size_t)wr * 1024 + (wc ^ (wr & 3)) * 8,
               Ws + z * 4096 + tid * 8);
  }
  int cur = 0;
  for (int kt = 0; kt < 32; ++kt) {
    __syncthreads();
    if (kt < 31) {
      const int k0 = (kt + 1) * 32;
      gl_lds16(X + (size_t)(m0 + xr) * 1024 + k0 + (xc32 ^ (xr & 3)) * 8 + xhf * 4,
               Xs + (cur ^ 1) * 2048 + tid * 4);
#pragma unroll
      for (int z = 0; z < 3; ++z)
        gl_lds16(Wt + (size_t)z * 131072 + (size_t)wr * 1024 + k0 + (wc ^ (wr & 3)) * 8,
                 Ws + (cur ^ 1) * 12288 + z * 4096 + tid * 8);
    }
    bf16x8 af[2];
#pragma unroll
    for (int mf = 0; mf < 2; ++mf) {
      int r = wm * 32 + mf * 16 + li;
      const float* xp = Xs + cur * 2048 + r * 32 + ((g ^ (r & 3)) * 8);
      f32x4 x0 = *(const f32x4*)xp;
      f32x4 x1 = *(const f32x4*)(xp + 4);
      union { bf16 h[8]; bf16x8 v; } u;
      u.h[0] = __float2bfloat16(x0[0]); u.h[1] = __float2bfloat16(x0[1]);
      u.h[2] = __float2bfloat16(x0[2]); u.h[3] = __float2bfloat16(x0[3]);
      u.h[4] = __float2bfloat16(x1[0]); u.h[5] = __float2bfloat16(x1[1]);
      u.h[6] = __float2bfloat16(x1[2]); u.h[7] = __float2bfloat16(x1[3]);
      af[mf] = u.v;
    }
#pragma unroll
    for (int z = 0; z < 3; ++z) {
#pragma unroll
      for (int nf = 0; nf < 2; ++nf) {
        int r = wn * 32 + nf * 16 + li;
        bf16x8 bfrag =
            *(const bf16x8*)(Ws + cur * 12288 + z * 4096 + r * 32 + ((g ^ (r & 3)) * 8));
#pragma unroll
        for (int mf = 0; mf < 2; ++mf)
          acc[z][mf][nf] = __builtin_amdgcn_mfma_f32_16x16x32_bf16(
              af[mf], bfrag, acc[z][mf][nf], 0, 0, 0);
      }
    }
    cur ^= 1;
  }

  // Q, K epilogue (row-major). Q scale = log2(e)/sqrt(128).
#pragma unroll
  for (int z = 0; z < 2; ++z) {
    const float* bias = z == 0 ? bq : bk;
    bf16* Out = z == 0 ? Qo : Ko;
    const float scale = z == 0 ? 0.12752404368678202f : 1.0f;
#pragma unroll
    for (int nf = 0; nf < 2; ++nf) {
      int col = wn * 32 + nf * 16 + li;
      float bb = bias[col];
#pragma unroll
      for (int mf = 0; mf < 2; ++mf)
#pragma unroll
        for (int j = 0; j < 4; ++j) {
          int row = m0 + wm * 32 + mf * 16 + g * 4 + j;
          Out[(size_t)row * 128 + col] =
              __float2bfloat16((acc[z][mf][nf][j] + bb) * scale);
        }
    }
  }

  // V epilogue: bounce through LDS, write transposed Vt [B][128][S].
  __syncthreads();  // main-loop LDS reads done before Vs overwrite
#pragma unroll
  for (int nf = 0; nf < 2; ++nf) {
    int col = wn * 32 + nf * 16 + li;
    float bb = bv[col];
#pragma unroll
    for (int mf = 0; mf < 2; ++mf)
#pragma unroll
      for (int j = 0; j < 4; ++j) {
        int row = wm * 32 + mf * 16 + g * 4 + j;
        Vs[row * 136 + col] = __float2bfloat16(acc[2][mf][nf][j] + bb);
      }
  }
  __syncthreads();
  const int b = m0 >> 12;
  const int s_off = m0 & 4095;
#pragma unroll
  for (int t2 = 0; t2 < 2; ++t2) {
    int idx = tid + 512 * t2;
    int dv = idx & 127;
    int sg = idx >> 7;
    union { bf16 h[8]; u32x4 v; } u;
#pragma unroll
    for (int si = 0; si < 8; ++si) u.h[si] = Vs[(sg * 8 + si) * 136 + dv];
    *(u32x4*)(Vt + (size_t)(b * 128 + dv) * 4096 + s_off + sg * 8) = u.v;
  }
}

// ---------------------------------------------------------------------------
// 3) causal flash attention. 256 thr = 4 waves x 16 q-rows (QBLK=64).
//    kv-chunks <=8 tiles: blocks/batch = 288, grid 1152 -> ~4.5 blocks/CU of
//    work, 4 resident (LDS 25.6KB, launch_bounds(256,4)). Single-buffered K,
//    2 barriers/tile, TLP hides staging. Swapped S^T + transposed PV (O^T).
//    P LDS: stride-72 rows, vectorized b64 store / b128 read, bank-minimal.
// ---------------------------------------------------------------------------
__global__ __launch_bounds__(256, 4) void k_attn(const bf16* __restrict__ Qb,
                                                 const bf16* __restrict__ Kb,
                                                 const bf16* __restrict__ Vt,
                                                 bf16* __restrict__ o_part,
                                                 float* __restrict__ l_part) {
  __shared__ __align__(16) bf16 Kls[64 * 128];   // 16 KB, swizzled chunks
  __shared__ __align__(16) bf16 Pls[4][16 * 72]; // per-wave P[q][kv], 9 KB

  const int bid = blockIdx.x;
  const int slot = (bid & 7) * 144 + (bid >> 3);  // XCD swizzle, bijective
  const int b = slot / 288;
  const int s = slot - b * 288;
  int kgrp = 0;
#pragma unroll
  for (int kk = 1; kk < 8; ++kk)
    if (4 * kk * (kk + 1) <= s) kgrp = kk;
  const int t = s - 4 * kgrp * (kgrp + 1);
  const int tq = t / (kgrp + 1);
  const int qt = 8 * kgrp + tq;
  const int chunk = t - tq * (kgrp + 1);
  const int s0 = qt * 64;
  const int kt0 = chunk * 8;
  const int kt1 = min(kt0 + 7, qt);

  const int tid = threadIdx.x;
  const int lane = tid & 63;
  const int li = lane & 15, g = lane >> 4;
  const int w = tid >> 6;

  // Q fragments (B-operand of swapped QK^T): lane holds Q[s0+w*16+li][...]
  bf16x8 qf[4];
#pragma unroll
  for (int ks = 0; ks < 4; ++ks)
    qf[ks] = *(const bf16x8*)(Qb +
        (size_t)(b * 4096 + s0 + w * 16 + li) * 128 + ks * 32 + g * 8);

  f32x4 o[8] = {};
  f32x4 lacc = {};
  bf16x8 ones;
#pragma unroll
  for (int e = 0; e < 8; ++e) ones[e] = (__bf16)1.0f;

  bf16* P = &Pls[w][0];
  const bf16* Vtb = Vt + (size_t)b * 128 * 4096;

  for (int kt = kt0; kt <= kt1; ++kt) {
    const int kv0 = kt * 64;
    // stage K tile (single buffer)
#pragma unroll
    for (int ii = 0; ii < 4; ++ii) {
      int c = tid + 256 * ii;
      int r = c >> 4, cc = c & 15;
      gl_lds16(Kb + (size_t)(b * 4096 + kv0 + r) * 128 + (cc ^ (r & 7)) * 8,
               &Kls[c * 8]);
    }
    __syncthreads();  // K ready

    // V prefetch, first half (kv 0..31): hides under QK^T
    bf16x8 vf0[8];
#pragma unroll
    for (int dvf = 0; dvf < 8; ++dvf)
      vf0[dvf] = *(const bf16x8*)(Vtb +
          (size_t)(dvf * 16 + li) * 4096 + kv0 + g * 8);

    // S^T = K Q^T : st[nf][j] = S^T[kv=nf*16+g*4+j][q=w*16+li]
    f32x4 st[4] = {};
#pragma unroll
    for (int ks = 0; ks < 4; ++ks) {
      bf16x8 kf[4];
#pragma unroll
      for (int nf = 0; nf < 4; ++nf) {
        int r = nf * 16 + li;
        int ch = (ks * 4 + g) ^ (r & 7);
        kf[nf] = *(const bf16x8*)(Kls + r * 128 + ch * 8);
      }
#pragma unroll
      for (int nf = 0; nf < 4; ++nf)
        st[nf] = __builtin_amdgcn_mfma_f32_16x16x32_bf16(
            kf[nf], qf[ks], st[nf], 0, 0, 0);
    }

    // V prefetch, second half (kv 32..63): hides under softmax + PV half 0
    bf16x8 vf1[8];
#pragma unroll
    for (int dvf = 0; dvf < 8; ++dvf)
      vf1[dvf] = *(const bf16x8*)(Vtb +
          (size_t)(dvf * 16 + li) * 4096 + kv0 + 32 + g * 8);

    if (kt == qt) {  // diagonal tile: causal mask (kv > q)
      const int qrow = w * 16 + li;
#pragma unroll
      for (int nf = 0; nf < 4; ++nf)
#pragma unroll
        for (int j = 0; j < 4; ++j)
          if (nf * 16 + g * 4 + j > qrow) st[nf][j] = -1e30f;
    }

    // P = exp2(S) -> b64 stores at P[li*72 + nf*16 + g*4] (bank-minimal)
#pragma unroll
    for (int nf = 0; nf < 4; ++nf) {
      union { bf16 h[4]; u32x2 v; } u;
#pragma unroll
      for (int j = 0; j < 4; ++j)
        u.h[j] = __float2bfloat16(exp2f(st[nf][j]));
      *(u32x2*)(P + li * 72 + nf * 16 + g * 4) = u.v;
    }

    // O^T += V^T P^T : o[dvf][j] = O^T[dv=dvf*16+g*4+j][q=w*16+li]
    {
      bf16x8 pa0 = *(const bf16x8*)(P + li * 72 + g * 8);
#pragma unroll
      for (int dvf = 0; dvf < 8; ++dvf)
        o[dvf] = __builtin_amdgcn_mfma_f32_16x16x32_bf16(
            vf0[dvf], pa0, o[dvf], 0, 0, 0);
      lacc = __builtin_amdgcn_mfma_f32_16x16x32_bf16(ones, pa0, lacc, 0, 0, 0);
      bf16x8 pa1 = *(const bf16x8*)(P + li * 72 + 32 + g * 8);
#pragma unroll
      for (int dvf = 0; dvf < 8; ++dvf)
        o[dvf] = __builtin_amdgcn_mfma_f32_16x16x32_bf16(
            vf1[dvf], pa1, o[dvf], 0, 0, 0);
      lacc = __builtin_amdgcn_mfma_f32_16x16x32_bf16(ones, pa1, lacc, 0, 0, 0);
    }
    __syncthreads();  // all waves done with Kls before next stage
  }

  // partials: O^T lane layout -> b64 stores; l replicated over rows (any j)
  bf16* op = o_part + (size_t)slot * (64 * 128);
  float* lp = l_part + slot * 64;
  if (g == 0) lp[w * 16 + li] = lacc[0];
#pragma unroll
  for (int dvf = 0; dvf < 8; ++dvf) {
    union { bf16 h[4]; u32x2 v; } u;
#pragma unroll
    for (int j = 0; j < 4; ++j) u.h[j] = __float2bfloat16(o[dvf][j]);
    *(u32x2*)(op + (size_t)(w * 16 + li) * 128 + dvf * 16 + g * 4) = u.v;
  }
}

// ---------------------------------------------------------------------------
// 4) combine chunk partials: out[row] = sum_c O_c[row] / sum_c l_c[row]
//    base(qt) = b*288 + (a+1)(4a + r), a = qt>>3, r = qt&7; n = a+1 (<=8).
// ---------------------------------------------------------------------------
__global__ __launch_bounds__(256) void k_comb(const bf16* __restrict__ op,
                                              const float* __restrict__ lp,
                                              float* __restrict__ out) {
  int i = blockIdx.x * 256 + threadIdx.x;  // 4-col group index, < 524288
  int row = i >> 5;
  int col4 = (i & 31) * 4;
  int b = row >> 12;
  int rb = row & 4095;
  int qt = rb >> 6;
  int lr = rb & 63;
  int a = qt >> 3, r = qt & 7;
  int base = b * 288 + (a + 1) * (4 * a + r);
  int n = a + 1;
  float l = 0.0f;
  float acc0 = 0, acc1 = 0, acc2 = 0, acc3 = 0;
  for (int c = 0; c < n; ++c) {
    l += lp[(base + c) * 64 + lr];
    union { bf16 h[4]; u32x2 v; } u;
    u.v = *(const u32x2*)(op + (size_t)(base + c) * 8192 + lr * 128 + col4);
    acc0 += __bfloat162float(u.h[0]);
    acc1 += __bfloat162float(u.h[1]);
    acc2 += __bfloat162float(u.h[2]);
    acc3 += __bfloat162float(u.h[3]);
  }
  float linv = 1.0f / l;
  float4 rv;
  rv.x = acc0 * linv; rv.y = acc1 * linv; rv.z = acc2 * linv; rv.w = acc3 * linv;
  ((float4*)out)[i] = rv;
}

// ---------------------------------------------------------------------------
extern "C" void kernel_launch(void* const* d_in, const int* in_sizes, int n_in,
                              void* d_out, int out_size, void* d_ws, size_t ws_size,
                              hipStream_t stream) {
  const float* X  = (const float*)d_in[0];
  const float* Wq = (const float*)d_in[1];
  const float* bq = (const float*)d_in[2];
  const float* Wk = (const float*)d_in[3];
  const float* bk = (const float*)d_in[4];
  const float* Wv = (const float*)d_in[5];
  const float* bv = (const float*)d_in[6];
  float* out = (float*)d_out;

  char* ws = (char*)d_ws;
  // layout (bytes) — fully disjoint, extent 32,538,624
  bf16* Wt  = (bf16*)(ws + 0);              //    786,432
  bf16* Qb  = (bf16*)(ws + 786432);         //  4,194,304
  bf16* Kb  = (bf16*)(ws + 4980736);        //  4,194,304
  bf16* Vt  = (bf16*)(ws + 9175040);        //  4,194,304
  bf16* o_part = (bf16*)(ws + 13369344);    // 18,874,368 (1152*64*128*2)
  float* l_part = (float*)(ws + 32243712);  //    294,912

  k_wt<<<dim3(16, 2, 3), dim3(256), 0, stream>>>(Wq, Wk, Wv, Wt);
  k_qkv<<<dim3(256), dim3(512), 0, stream>>>(X, Wt, bq, bk, bv, Qb, Kb, Vt);
  k_attn<<<dim3(1152), dim3(256), 0, stream>>>(Qb, Kb, Vt, o_part, l_part);
  k_comb<<<dim3(2048), dim3(256), 0, stream>>>(o_part, l_part, out);
}

// Round 6
// 142.810 us; speedup vs baseline: 1.4235x; 1.4235x over previous
//
#include <hip/hip_runtime.h>
#include <hip/hip_bf16.h>
#include <stdint.h>

// ============================================================================
// Fused causal self-attention block: QKV projection + flash attention.
// bf16 MFMA. No-max softmax (scores bounded; log2e folded into Q scale).
// Swapped QK^T (S^T) + transposed PV (O^T). P LDS layout stride-72, b64
// stores / b128 reads (2-way max bank aliasing = free). kv-chunks <=16 tiles
// -> 640 blocks x 4 waves; K double-buffered (one barrier/tile); V direct
// from L2-resident Vt panel. V transposed inside k_qkv epilogue.
// ============================================================================

typedef __bf16 bf16x8 __attribute__((ext_vector_type(8)));
typedef float  f32x4  __attribute__((ext_vector_type(4)));
typedef unsigned int u32x4 __attribute__((ext_vector_type(4)));
typedef unsigned int u32x2 __attribute__((ext_vector_type(2)));

using bf16 = __hip_bfloat16;

#define AS1 __attribute__((address_space(1)))
#define AS3 __attribute__((address_space(3)))

__device__ __forceinline__ void gl_lds16(const void* g, void* l) {
  __builtin_amdgcn_global_load_lds((AS1 uint32_t*)g, (AS3 uint32_t*)l, 16, 0, 0);
}

// ---------------------------------------------------------------------------
// 1) W [1024][128] fp32 -> Wt[z][128][1024] bf16 (transpose via LDS tile)
// ---------------------------------------------------------------------------
__global__ __launch_bounds__(256) void k_wt(const float* __restrict__ Wq,
                                            const float* __restrict__ Wk,
                                            const float* __restrict__ Wv,
                                            bf16* __restrict__ Wt) {
  __shared__ bf16 t[64][72];
  const float* W = blockIdx.z == 0 ? Wq : (blockIdx.z == 1 ? Wk : Wv);
  int k0 = blockIdx.x * 64, n0 = blockIdx.y * 64;
  int tid = threadIdx.x;
  int r = tid >> 4, c4 = (tid & 15) * 4;
#pragma unroll
  for (int s = 0; s < 4; ++s) {
    int rr = r + s * 16;
    float4 v = *(const float4*)(W + (size_t)(k0 + rr) * 128 + n0 + c4);
    t[rr][c4 + 0] = __float2bfloat16(v.x);
    t[rr][c4 + 1] = __float2bfloat16(v.y);
    t[rr][c4 + 2] = __float2bfloat16(v.z);
    t[rr][c4 + 3] = __float2bfloat16(v.w);
  }
  __syncthreads();
  bf16* out = Wt + (size_t)blockIdx.z * 128 * 1024;
#pragma unroll
  for (int s = 0; s < 4; ++s) {
    int rn = r + s * 16;
    union { bf16 h[4]; u32x2 v; } u;
    u.h[0] = t[c4 + 0][rn]; u.h[1] = t[c4 + 1][rn];
    u.h[2] = t[c4 + 2][rn]; u.h[3] = t[c4 + 3][rn];
    *(u32x2*)(out + (size_t)(n0 + rn) * 1024 + k0 + c4) = u.v;
  }
}

// ---------------------------------------------------------------------------
// 2) fused QKV projection + in-kernel V transpose. Reads f32 X once.
//    BM=64, BK=32, 512 thr = 8 waves (2x4). Q pre-scaled log2(e)/sqrt(128).
//    Epilogue: Q,K row-major; V bounced through LDS -> Vt [B][128][S].
// ---------------------------------------------------------------------------
__global__ __launch_bounds__(512) void k_qkv(const float* __restrict__ X,
                                             const bf16* __restrict__ Wt,
                                             const float* __restrict__ bq,
                                             const float* __restrict__ bk,
                                             const float* __restrict__ bv,
                                             bf16* __restrict__ Qo,
                                             bf16* __restrict__ Ko,
                                             bf16* __restrict__ Vt) {
  __shared__ __align__(16) char smem[65536];
  float* Xs = (float*)smem;                  // [2][64*32] f32, 16 KB
  bf16* Ws = (bf16*)(smem + 16384);          // [2][3*128*32] bf16, 48 KB
  bf16* Vs = (bf16*)smem;                    // epilogue: [64][136], 17.4 KB

  const int m0 = blockIdx.x * 64;
  const int tid = threadIdx.x;
  const int lane = tid & 63;
  const int li = lane & 15, g = lane >> 4;
  const int wid = tid >> 6;
  const int wm = wid >> 2, wn = wid & 3;

  const int xr = tid >> 3;
  const int xc32 = (tid & 7) >> 1;
  const int xhf = tid & 1;
  const int wr = tid >> 2;
  const int wc = tid & 3;

  f32x4 acc[3][2][2] = {};

  {
    gl_lds16(X + (size_t)(m0 + xr) * 1024 + (xc32 ^ (xr & 3)) * 8 + xhf * 4,
             Xs + tid * 4);
#pragma unroll
    for (int z = 0; z < 3; ++z)
      gl_lds16(Wt + (size_t)z * 131072 + (size_t)wr * 1024 + (wc ^ (wr & 3)) * 8,
               Ws + z * 4096 + tid * 8);
  }
  int cur = 0;
  for (int kt = 0; kt < 32; ++kt) {
    __syncthreads();
    if (kt < 31) {
      const int k0 = (kt + 1) * 32;
      gl_lds16(X + (size_t)(m0 + xr) * 1024 + k0 + (xc32 ^ (xr & 3)) * 8 + xhf * 4,
               Xs + (cur ^ 1) * 2048 + tid * 4);
#pragma unroll
      for (int z = 0; z < 3; ++z)
        gl_lds16(Wt + (size_t)z * 131072 + (size_t)wr * 1024 + k0 + (wc ^ (wr & 3)) * 8,
                 Ws + (cur ^ 1) * 12288 + z * 4096 + tid * 8);
    }
    bf16x8 af[2];
#pragma unroll
    for (int mf = 0; mf < 2; ++mf) {
      int r = wm * 32 + mf * 16 + li;
      const float* xp = Xs + cur * 2048 + r * 32 + ((g ^ (r & 3)) * 8);
      f32x4 x0 = *(const f32x4*)xp;
      f32x4 x1 = *(const f32x4*)(xp + 4);
      union { bf16 h[8]; bf16x8 v; } u;
      u.h[0] = __float2bfloat16(x0[0]); u.h[1] = __float2bfloat16(x0[1]);
      u.h[2] = __float2bfloat16(x0[2]); u.h[3] = __float2bfloat16(x0[3]);
      u.h[4] = __float2bfloat16(x1[0]); u.h[5] = __float2bfloat16(x1[1]);
      u.h[6] = __float2bfloat16(x1[2]); u.h[7] = __float2bfloat16(x1[3]);
      af[mf] = u.v;
    }
#pragma unroll
    for (int z = 0; z < 3; ++z) {
#pragma unroll
      for (int nf = 0; nf < 2; ++nf) {
        int r = wn * 32 + nf * 16 + li;
        bf16x8 bfrag =
            *(const bf16x8*)(Ws + cur * 12288 + z * 4096 + r * 32 + ((g ^ (r & 3)) * 8));
#pragma unroll
        for (int mf = 0; mf < 2; ++mf)
          acc[z][mf][nf] = __builtin_amdgcn_mfma_f32_16x16x32_bf16(
              af[mf], bfrag, acc[z][mf][nf], 0, 0, 0);
      }
    }
    cur ^= 1;
  }

  // Q, K epilogue (row-major). Q scale = log2(e)/sqrt(128).
#pragma unroll
  for (int z = 0; z < 2; ++z) {
    const float* bias = z == 0 ? bq : bk;
    bf16* Out = z == 0 ? Qo : Ko;
    const float scale = z == 0 ? 0.12752404368678202f : 1.0f;
#pragma unroll
    for (int nf = 0; nf < 2; ++nf) {
      int col = wn * 32 + nf * 16 + li;
      float bb = bias[col];
#pragma unroll
      for (int mf = 0; mf < 2; ++mf)
#pragma unroll
        for (int j = 0; j < 4; ++j) {
          int row = m0 + wm * 32 + mf * 16 + g * 4 + j;
          Out[(size_t)row * 128 + col] =
              __float2bfloat16((acc[z][mf][nf][j] + bb) * scale);
        }
    }
  }

  // V epilogue: bounce through LDS, write transposed Vt [B][128][S].
  __syncthreads();  // main-loop LDS reads done before Vs overwrite
#pragma unroll
  for (int nf = 0; nf < 2; ++nf) {
    int col = wn * 32 + nf * 16 + li;
    float bb = bv[col];
#pragma unroll
    for (int mf = 0; mf < 2; ++mf)
#pragma unroll
      for (int j = 0; j < 4; ++j) {
        int row = wm * 32 + mf * 16 + g * 4 + j;
        Vs[row * 136 + col] = __float2bfloat16(acc[2][mf][nf][j] + bb);
      }
  }
  __syncthreads();
  const int b = m0 >> 12;
  const int s_off = m0 & 4095;
#pragma unroll
  for (int t2 = 0; t2 < 2; ++t2) {
    int idx = tid + 512 * t2;
    int dv = idx & 127;
    int sg = idx >> 7;
    union { bf16 h[8]; u32x4 v; } u;
#pragma unroll
    for (int si = 0; si < 8; ++si) u.h[si] = Vs[(sg * 8 + si) * 136 + dv];
    *(u32x4*)(Vt + (size_t)(b * 128 + dv) * 4096 + s_off + sg * 8) = u.v;
  }
}

// ---------------------------------------------------------------------------
// 3) causal flash attention. 256 thr = 4 waves x 16 q-rows (QBLK=64).
//    kv-chunks <=16 tiles: 160 blocks/batch, grid 640 (~2.5 work-blocks/CU,
//    3 resident at 41,984B LDS). K double-buffered, ONE barrier per tile.
//    Swapped S^T + transposed PV (O^T). P LDS stride-72, b64/b128,
//    worst-case 2-way bank aliasing (free). V direct from L2-resident Vt.
// ---------------------------------------------------------------------------
__global__ __launch_bounds__(256) void k_attn(const bf16* __restrict__ Qb,
                                              const bf16* __restrict__ Kb,
                                              const bf16* __restrict__ Vt,
                                              bf16* __restrict__ o_part,
                                              float* __restrict__ l_part) {
  __shared__ __align__(16) bf16 Kls[2][64 * 128];  // 32 KB, swizzled chunks
  __shared__ __align__(16) bf16 Pls[4][16 * 72];   // per-wave P[q][kv], 9 KB

  const int bid = blockIdx.x;
  const int slot = (bid & 7) * 80 + (bid >> 3);  // XCD swizzle, bijective
  const int b = slot / 160;
  const int s = slot - b * 160;
  const int a = (s >= 96) ? 3 : (s >= 48) ? 2 : (s >= 16) ? 1 : 0;
  const int t = s - 8 * a * (a + 1);
  const int tq = t / (a + 1);
  const int qt = 16 * a + tq;
  const int chunk = t - tq * (a + 1);
  const int s0 = qt * 64;
  const int kt0 = chunk * 16;
  const int kt1 = min(kt0 + 15, qt);

  const int tid = threadIdx.x;
  const int lane = tid & 63;
  const int li = lane & 15, g = lane >> 4;
  const int w = tid >> 6;

  // Q fragments (B-operand of swapped QK^T): lane holds Q[s0+w*16+li][...]
  bf16x8 qf[4];
#pragma unroll
  for (int ks = 0; ks < 4; ++ks)
    qf[ks] = *(const bf16x8*)(Qb +
        (size_t)(b * 4096 + s0 + w * 16 + li) * 128 + ks * 32 + g * 8);

  f32x4 o[8] = {};
  f32x4 lacc = {};
  bf16x8 ones;
#pragma unroll
  for (int e = 0; e < 8; ++e) ones[e] = (__bf16)1.0f;

  bf16* P = &Pls[w][0];
  const bf16* Vtb = Vt + (size_t)b * 128 * 4096;

  // prologue: stage K tile kt0 -> buf 0
#pragma unroll
  for (int ii = 0; ii < 4; ++ii) {
    int c = tid + 256 * ii;
    int r = c >> 4, cc = c & 15;
    gl_lds16(Kb + (size_t)(b * 4096 + kt0 * 64 + r) * 128 + (cc ^ (r & 7)) * 8,
             &Kls[0][c * 8]);
  }
  int cur = 0;
  for (int kt = kt0; kt <= kt1; ++kt) {
    __syncthreads();  // buf[cur] staged; all waves done reading buf[cur^1]
    if (kt < kt1) {
      const int kv0n = (kt + 1) * 64;
#pragma unroll
      for (int ii = 0; ii < 4; ++ii) {
        int c = tid + 256 * ii;
        int r = c >> 4, cc = c & 15;
        gl_lds16(Kb + (size_t)(b * 4096 + kv0n + r) * 128 + (cc ^ (r & 7)) * 8,
                 &Kls[cur ^ 1][c * 8]);
      }
    }
    const bf16* Kl = &Kls[cur][0];
    const int kv0 = kt * 64;

    // V prefetch, first half (kv 0..31): hides under QK^T
    bf16x8 vf0[8];
#pragma unroll
    for (int dvf = 0; dvf < 8; ++dvf)
      vf0[dvf] = *(const bf16x8*)(Vtb +
          (size_t)(dvf * 16 + li) * 4096 + kv0 + g * 8);

    // S^T = K Q^T : st[nf][j] = S^T[kv=nf*16+g*4+j][q=w*16+li]
    f32x4 st[4] = {};
#pragma unroll
    for (int ks = 0; ks < 4; ++ks) {
      bf16x8 kf[4];
#pragma unroll
      for (int nf = 0; nf < 4; ++nf) {
        int r = nf * 16 + li;
        int ch = (ks * 4 + g) ^ (r & 7);
        kf[nf] = *(const bf16x8*)(Kl + r * 128 + ch * 8);
      }
#pragma unroll
      for (int nf = 0; nf < 4; ++nf)
        st[nf] = __builtin_amdgcn_mfma_f32_16x16x32_bf16(
            kf[nf], qf[ks], st[nf], 0, 0, 0);
    }

    // V prefetch, second half (kv 32..63)
    bf16x8 vf1[8];
#pragma unroll
    for (int dvf = 0; dvf < 8; ++dvf)
      vf1[dvf] = *(const bf16x8*)(Vtb +
          (size_t)(dvf * 16 + li) * 4096 + kv0 + 32 + g * 8);

    if (kt == qt) {  // diagonal tile: causal mask (kv > q)
      const int qrow = w * 16 + li;
#pragma unroll
      for (int nf = 0; nf < 4; ++nf)
#pragma unroll
        for (int j = 0; j < 4; ++j)
          if (nf * 16 + g * 4 + j > qrow) st[nf][j] = -1e30f;
    }

    // P = exp2(S) -> b64 stores at P[li*72 + nf*16 + g*4] (2-way max)
#pragma unroll
    for (int nf = 0; nf < 4; ++nf) {
      union { bf16 h[4]; u32x2 v; } u;
#pragma unroll
      for (int j = 0; j < 4; ++j)
        u.h[j] = __float2bfloat16(exp2f(st[nf][j]));
      *(u32x2*)(P + li * 72 + nf * 16 + g * 4) = u.v;
    }

    // O^T += V^T P^T : o[dvf][j] = O^T[dv=dvf*16+g*4+j][q=w*16+li]
    {
      bf16x8 pa0 = *(const bf16x8*)(P + li * 72 + g * 8);
#pragma unroll
      for (int dvf = 0; dvf < 8; ++dvf)
        o[dvf] = __builtin_amdgcn_mfma_f32_16x16x32_bf16(
            vf0[dvf], pa0, o[dvf], 0, 0, 0);
      lacc = __builtin_amdgcn_mfma_f32_16x16x32_bf16(ones, pa0, lacc, 0, 0, 0);
      bf16x8 pa1 = *(const bf16x8*)(P + li * 72 + 32 + g * 8);
#pragma unroll
      for (int dvf = 0; dvf < 8; ++dvf)
        o[dvf] = __builtin_amdgcn_mfma_f32_16x16x32_bf16(
            vf1[dvf], pa1, o[dvf], 0, 0, 0);
      lacc = __builtin_amdgcn_mfma_f32_16x16x32_bf16(ones, pa1, lacc, 0, 0, 0);
    }
    cur ^= 1;
  }

  // partials: O^T lane layout -> b64 stores; l replicated over rows
  bf16* op = o_part + (size_t)slot * (64 * 128);
  float* lp = l_part + slot * 64;
  if (g == 0) lp[w * 16 + li] = lacc[0];
#pragma unroll
  for (int dvf = 0; dvf < 8; ++dvf) {
    union { bf16 h[4]; u32x2 v; } u;
#pragma unroll
    for (int j = 0; j < 4; ++j) u.h[j] = __float2bfloat16(o[dvf][j]);
    *(u32x2*)(op + (size_t)(w * 16 + li) * 128 + dvf * 16 + g * 4) = u.v;
  }
}

// ---------------------------------------------------------------------------
// 4) combine chunk partials: out[row] = sum_c O_c[row] / sum_c l_c[row]
//    base(qt) = b*160 + (a+1)(8a + r), a = qt>>4, r = qt&15; n = a+1 (<=4).
// ---------------------------------------------------------------------------
__global__ __launch_bounds__(256) void k_comb(const bf16* __restrict__ op,
                                              const float* __restrict__ lp,
                                              float* __restrict__ out) {
  int i = blockIdx.x * 256 + threadIdx.x;  // 4-col group index, < 524288
  int row = i >> 5;
  int col4 = (i & 31) * 4;
  int b = row >> 12;
  int rb = row & 4095;
  int qt = rb >> 6;
  int lr = rb & 63;
  int a = qt >> 4, r = qt & 15;
  int base = b * 160 + (a + 1) * (8 * a + r);
  int n = a + 1;
  float l = 0.0f;
  float acc0 = 0, acc1 = 0, acc2 = 0, acc3 = 0;
  for (int c = 0; c < n; ++c) {
    l += lp[(base + c) * 64 + lr];
    union { bf16 h[4]; u32x2 v; } u;
    u.v = *(const u32x2*)(op + (size_t)(base + c) * 8192 + lr * 128 + col4);
    acc0 += __bfloat162float(u.h[0]);
    acc1 += __bfloat162float(u.h[1]);
    acc2 += __bfloat162float(u.h[2]);
    acc3 += __bfloat162float(u.h[3]);
  }
  float linv = 1.0f / l;
  float4 rv;
  rv.x = acc0 * linv; rv.y = acc1 * linv; rv.z = acc2 * linv; rv.w = acc3 * linv;
  ((float4*)out)[i] = rv;
}

// ---------------------------------------------------------------------------
extern "C" void kernel_launch(void* const* d_in, const int* in_sizes, int n_in,
                              void* d_out, int out_size, void* d_ws, size_t ws_size,
                              hipStream_t stream) {
  const float* X  = (const float*)d_in[0];
  const float* Wq = (const float*)d_in[1];
  const float* bq = (const float*)d_in[2];
  const float* Wk = (const float*)d_in[3];
  const float* bk = (const float*)d_in[4];
  const float* Wv = (const float*)d_in[5];
  const float* bv = (const float*)d_in[6];
  float* out = (float*)d_out;

  char* ws = (char*)d_ws;
  // layout (bytes) — fully disjoint, extent 24,018,944
  bf16* Wt  = (bf16*)(ws + 0);              //    786,432
  bf16* Qb  = (bf16*)(ws + 786432);         //  4,194,304
  bf16* Kb  = (bf16*)(ws + 4980736);        //  4,194,304
  bf16* Vt  = (bf16*)(ws + 9175040);        //  4,194,304
  bf16* o_part = (bf16*)(ws + 13369344);    // 10,485,760 (640*64*128*2)
  float* l_part = (float*)(ws + 23855104);  //    163,840

  k_wt<<<dim3(16, 2, 3), dim3(256), 0, stream>>>(Wq, Wk, Wv, Wt);
  k_qkv<<<dim3(256), dim3(512), 0, stream>>>(X, Wt, bq, bk, bv, Qb, Kb, Vt);
  k_attn<<<dim3(640), dim3(256), 0, stream>>>(Qb, Kb, Vt, o_part, l_part);
  k_comb<<<dim3(2048), dim3(256), 0, stream>>>(o_part, l_part, out);
}